// Round 1
// baseline (1466.438 us; speedup 1.0000x reference)
//
#include <hip/hip_runtime.h>

// Problem constants (from reference setup_inputs)
constexpr int T_  = 4;
constexpr int B_  = 32;
constexpr int N_  = 1024;
constexpr int D_  = 512;
constexpr int O_  = 512;
constexpr int OP_ = 256;   // O_/K pooled features

// Tile config
constexpr int SITES = 32;   // (b,n) sites per block
constexpr int ROWS  = 128;  // SITES * T_  (rows ordered r = s*4 + t)
constexpr int BN    = 64;   // output cols per block
constexpr int BK    = 16;   // K-tile

__global__ __launch_bounds__(256)
void snn_fused_f64(const float* __restrict__ x, const float* __restrict__ W,
                   const float* __restrict__ gamma, const float* __restrict__ beta,
                   const float* __restrict__ rmean, const float* __restrict__ rvar,
                   float* __restrict__ out)
{
    __shared__ float As[BK][ROWS];  // [k][r], r = site*4 + t  (row-contiguous for b128 reads)
    __shared__ float Bs[BK][BN];    // [k][c]

    const int tid = threadIdx.x;
    const int tx  = tid & 15;   // col group: owns cols tx*4 .. tx*4+3
    const int ty  = tid >> 4;   // row group: owns rows ty*8 .. ty*8+7 (= 2 sites x 4 t)

    const int c0        = blockIdx.x * BN;      // 0..511 step 64
    const int site_base = blockIdx.y * SITES;   // global flattened (b*N + n), multiple of 32
    const int b  = site_base / N_;              // whole tile lies in one b (N_ % SITES == 0)
    const int n0 = site_base % N_;

    // ---- A loader mapping: 2 threads per row, 8 contiguous k each ----
    const int lrow = tid >> 1;        // 0..127  (= s*4 + t)
    const int lk   = (tid & 1) * 8;   // 0 or 8
    const int s_l  = lrow >> 2;
    const int t_l  = lrow & 3;
    const float* xrow = x + (size_t)((t_l * B_ + b) * N_ + (n0 + s_l)) * D_ + lk;

    // ---- W loader mapping: thread -> (col, 4 contiguous k) ----
    const int wc = tid & 63;
    const int wk = (tid >> 6) * 4;
    const float* wrow = W + (size_t)(c0 + wc) * D_ + wk;

    double acc[8][4];
    #pragma unroll
    for (int i = 0; i < 8; ++i)
        #pragma unroll
        for (int j = 0; j < 4; ++j) acc[i][j] = 0.0;

    for (int k0 = 0; k0 < D_; k0 += BK) {
        const float4 a0 = *(const float4*)(xrow + k0);
        const float4 a1 = *(const float4*)(xrow + k0 + 4);
        const float4 w4 = *(const float4*)(wrow + k0);

        As[lk + 0][lrow] = a0.x;  As[lk + 1][lrow] = a0.y;
        As[lk + 2][lrow] = a0.z;  As[lk + 3][lrow] = a0.w;
        As[lk + 4][lrow] = a1.x;  As[lk + 5][lrow] = a1.y;
        As[lk + 6][lrow] = a1.z;  As[lk + 7][lrow] = a1.w;

        Bs[wk + 0][wc] = w4.x;  Bs[wk + 1][wc] = w4.y;
        Bs[wk + 2][wc] = w4.z;  Bs[wk + 3][wc] = w4.w;

        __syncthreads();

        #pragma unroll
        for (int k = 0; k < BK; ++k) {
            const float4 af0 = *(const float4*)&As[k][ty * 8];
            const float4 af1 = *(const float4*)&As[k][ty * 8 + 4];
            const float4 bf  = *(const float4*)&Bs[k][tx * 4];
            const double ad[8] = {(double)af0.x, (double)af0.y, (double)af0.z, (double)af0.w,
                                  (double)af1.x, (double)af1.y, (double)af1.z, (double)af1.w};
            const double bd[4] = {(double)bf.x, (double)bf.y, (double)bf.z, (double)bf.w};
            #pragma unroll
            for (int i = 0; i < 8; ++i)
                #pragma unroll
                for (int j = 0; j < 4; ++j)
                    acc[i][j] = fma(ad[i], bd[j], acc[i][j]);
        }
        __syncthreads();
    }

    // ---- Epilogue: BN affine -> pool pairs -> LIF over t, all in f64 ----
    double invd[4], addd[4];
    #pragma unroll
    for (int j = 0; j < 4; ++j) {
        const int c = c0 + tx * 4 + j;
        const double iv = (double)gamma[c] / sqrt((double)rvar[c] + 1e-5);
        invd[j] = iv;
        addd[j] = (double)beta[c] - (double)rmean[c] * iv;
    }

    #pragma unroll
    for (int si = 0; si < 2; ++si) {
        const int n = n0 + ty * 2 + si;
        #pragma unroll
        for (int p = 0; p < 2; ++p) {
            const int op = (c0 >> 1) + tx * 2 + p;
            double v = 0.0;
            #pragma unroll
            for (int t = 0; t < 4; ++t) {
                const int i = si * 4 + t;
                const double h0 = acc[i][2 * p]     * invd[2 * p]     + addd[2 * p];
                const double h1 = acc[i][2 * p + 1] * invd[2 * p + 1] + addd[2 * p + 1];
                const double m  = fmax(h0, h1);
                v = v + (m - v) * 0.5;              // v += (x - v)/tau, tau = 2
                const bool sp = (v >= 1.0);         // spike(v - 1)
                out[((size_t)(t * B_ + b) * N_ + n) * OP_ + op] = sp ? 1.0f : 0.0f;
                if (sp) v = 0.0;                    // hard reset
            }
        }
    }
}

extern "C" void kernel_launch(void* const* d_in, const int* in_sizes, int n_in,
                              void* d_out, int out_size, void* d_ws, size_t ws_size,
                              hipStream_t stream)
{
    const float* x     = (const float*)d_in[0];
    const float* W     = (const float*)d_in[1];
    const float* gamma = (const float*)d_in[2];
    const float* beta  = (const float*)d_in[3];
    const float* rmean = (const float*)d_in[4];
    const float* rvar  = (const float*)d_in[5];
    float* out = (float*)d_out;

    dim3 grid(O_ / BN, (B_ * N_) / SITES);  // (8, 1024); col-block fastest => A-tile L2 reuse
    snn_fused_f64<<<grid, dim3(256), 0, stream>>>(x, W, gamma, beta, rmean, rvar, out);
}

// Round 2
// 692.442 us; speedup vs baseline: 2.1178x; 2.1178x over previous
//
#include <hip/hip_runtime.h>

constexpr int T_ = 4, B_ = 32, N_ = 1024, D_ = 512, O_ = 512, OP_ = 256;
constexpr int M_ = T_ * B_ * N_;               // 131072 GEMM rows (ordered site*4 + t)
constexpr unsigned CAP = 2u * 1024 * 1024;     // repair-list capacity

// ---- ws layout (bytes) ----
constexpr size_t WS_CNT  = 0;
constexpr size_t WS_WH   = 1u << 20;
constexpr size_t WS_WM   = WS_WH + (size_t)O_ * D_ * 2;
constexpr size_t WS_XH   = 2u << 20;
constexpr size_t WS_XM   = WS_XH + (size_t)M_ * D_ * 2;
constexpr size_t WS_LIST = WS_XM + (size_t)M_ * D_ * 2;
constexpr size_t WS_NEED = WS_LIST + (size_t)CAP * 4;

typedef __attribute__((ext_vector_type(8))) short bf8;
typedef __attribute__((ext_vector_type(4))) float f4;

__device__ __forceinline__ unsigned short f2bf(float f) {
    unsigned u = __float_as_uint(f);
    unsigned r = (u + 0x7FFFu + ((u >> 16) & 1u)) >> 16;   // RNE
    return (unsigned short)r;
}
__device__ __forceinline__ float bf2f(unsigned short h) {
    return __uint_as_float(((unsigned)h) << 16);
}

// ---------------- init ----------------
__global__ void k_init(unsigned* cnt) { if (threadIdx.x == 0) *cnt = 0u; }

// ---------------- split W -> wh, wm (bf16) ----------------
__global__ void k_split_w(const float* __restrict__ W, unsigned short* __restrict__ wh,
                          unsigned short* __restrict__ wm) {
    const int c = blockIdx.x;
    const int d = threadIdx.x * 2;
    float2 v = *(const float2*)(W + (size_t)c * D_ + d);
    unsigned short h0 = f2bf(v.x), h1 = f2bf(v.y);
    unsigned short m0 = f2bf(v.x - bf2f(h0)), m1 = f2bf(v.y - bf2f(h1));
    *(ushort2*)(wh + (size_t)c * D_ + d) = make_ushort2(h0, h1);
    *(ushort2*)(wm + (size_t)c * D_ + d) = make_ushort2(m0, m1);
}

// ---------------- split + reorder x -> xh, xm (row = (b*N+n)*4 + t) ----------------
__global__ void k_split_x(const float* __restrict__ x, unsigned short* __restrict__ xh,
                          unsigned short* __restrict__ xm) {
    const int rin = blockIdx.x;                 // (t*B + b)*N + n
    const int d = threadIdx.x * 4;
    const int t = rin >> 15, b = (rin >> 10) & 31, n = rin & 1023;
    const int rout = (((b << 10) | n) << 2) | t;
    float4 v = *(const float4*)(x + (size_t)rin * D_ + d);
    unsigned short h0 = f2bf(v.x), h1 = f2bf(v.y), h2 = f2bf(v.z), h3 = f2bf(v.w);
    unsigned short m0 = f2bf(v.x - bf2f(h0)), m1 = f2bf(v.y - bf2f(h1));
    unsigned short m2 = f2bf(v.z - bf2f(h2)), m3 = f2bf(v.w - bf2f(h3));
    *(ushort4*)(xh + (size_t)rout * D_ + d) = make_ushort4(h0, h1, h2, h3);
    *(ushort4*)(xm + (size_t)rout * D_ + d) = make_ushort4(m0, m1, m2, m3);
}

// ---------------- fast fused pass: MFMA GEMM + BN/pool/LIF + flagging ----------------
__global__ __launch_bounds__(256) void k_gemm(
    const unsigned short* __restrict__ xh, const unsigned short* __restrict__ xm,
    const unsigned short* __restrict__ wh, const unsigned short* __restrict__ wm,
    const float* __restrict__ gamma, const float* __restrict__ beta,
    const float* __restrict__ rmean, const float* __restrict__ rvar,
    float* __restrict__ out, unsigned* __restrict__ cnt, unsigned* __restrict__ list)
{
    extern __shared__ char lds[];   // [dbuf:2][term:2][row:128][128B], 64 KiB
    const int tid  = threadIdx.x;
    const int lane = tid & 63;
    const int wid  = tid >> 6;

    // XCD-aware swizzle: each XCD gets a contiguous range of work ids
    const int dd = blockIdx.x;                  // 0..4095
    const int w  = (dd & 7) * 512 + (dd >> 3);
    const int colblk = w & 3, rowblk = w >> 2;
    const int c0  = colblk * 128;
    const int wr0 = (wid >> 1) * 64, wc0 = (wid & 1) * 64;

    // ---- staging source (pre-swizzled so linear LDS dest = swizzled layout) ----
    const int srow = tid >> 3;                              // 0..31
    const int skb  = ((tid & 7) << 4) ^ ((srow & 7) << 4);  // byte within 128B row
    const char* gA0 = (const char*)xh + ((size_t)(rowblk * 128 + srow)) * 1024 + skb;
    const char* gA1 = (const char*)xm + ((size_t)(rowblk * 128 + srow)) * 1024 + skb;

    // ---- B per-lane byte offsets: even/odd column split ----
    size_t bOff[2][2];  // [cf][eo]
    #pragma unroll
    for (int cf = 0; cf < 2; ++cf)
        #pragma unroll
        for (int eo = 0; eo < 2; ++eo) {
            int c = c0 + wc0 + cf * 32 + 2 * (lane & 15) + eo;
            bOff[cf][eo] = (size_t)c * 1024 + ((size_t)(lane >> 4) << 4);
        }

    // ---- BN constants (f32; any deviation covered by flag+repair) ----
    float invE[2], addE[2], invO[2], addO[2];
    #pragma unroll
    for (int cf = 0; cf < 2; ++cf) {
        int cE = c0 + wc0 + cf * 32 + 2 * (lane & 15);
        int cO = cE + 1;
        float ivE = gamma[cE] / sqrtf(rvar[cE] + 1e-5f);
        float ivO = gamma[cO] / sqrtf(rvar[cO] + 1e-5f);
        invE[cf] = ivE; addE[cf] = beta[cE] - rmean[cE] * ivE;
        invO[cf] = ivO; addO[cf] = beta[cO] - rmean[cO] * ivO;
    }

    f4 accE[4][2], accO[4][2];
    #pragma unroll
    for (int i = 0; i < 4; ++i)
        #pragma unroll
        for (int j = 0; j < 2; ++j) { accE[i][j] = (f4)0.0f; accO[i][j] = (f4)0.0f; }

#define STAGE(buf, step)                                                                   \
    {                                                                                      \
        _Pragma("unroll")                                                                  \
        for (int i = 0; i < 4; ++i) {                                                      \
            __builtin_amdgcn_global_load_lds(                                              \
                (const __attribute__((address_space(1))) void*)(gA0 + (size_t)i * 32768 +  \
                                                                (step) * 128),             \
                (__attribute__((address_space(3))) void*)(lds + (buf) * 32768 + 0 +        \
                                                          i * 4096 + wid * 1024),          \
                16, 0, 0);                                                                 \
            __builtin_amdgcn_global_load_lds(                                              \
                (const __attribute__((address_space(1))) void*)(gA1 + (size_t)i * 32768 +  \
                                                                (step) * 128),             \
                (__attribute__((address_space(3))) void*)(lds + (buf) * 32768 + 16384 +    \
                                                          i * 4096 + wid * 1024),          \
                16, 0, 0);                                                                 \
        }                                                                                  \
    }

    STAGE(0, 0);
    __syncthreads();

    const char* whB = (const char*)wh;
    const char* wmB = (const char*)wm;

    for (int step = 0; step < 8; ++step) {
        const int dbuf = step & 1;
        if (step < 7) STAGE(dbuf ^ 1, step + 1);

        // B fragments for this K-step: [term][cf][eo][ksub]
        bf8 Bf[2][2][2][2];
        #pragma unroll
        for (int cf = 0; cf < 2; ++cf)
            #pragma unroll
            for (int eo = 0; eo < 2; ++eo)
                #pragma unroll
                for (int ks = 0; ks < 2; ++ks) {
                    Bf[0][cf][eo][ks] = *(const bf8*)(whB + bOff[cf][eo] + step * 128 + ks * 64);
                    Bf[1][cf][eo][ks] = *(const bf8*)(wmB + bOff[cf][eo] + step * 128 + ks * 64);
                }

        #pragma unroll
        for (int rf = 0; rf < 4; ++rf) {
            const int row = wr0 + rf * 16 + (lane & 15);
            const int X = (row & 7) << 4;
            const char* ab = lds + dbuf * 32768 + row * 128;
            bf8 a[2][2];  // [term][ksub]
            #pragma unroll
            for (int ks = 0; ks < 2; ++ks) {
                const int cb = ks * 64 + ((lane >> 4) << 4);
                a[0][ks] = *(const bf8*)(ab + 0     + (cb ^ X));
                a[1][ks] = *(const bf8*)(ab + 16384 + (cb ^ X));
            }
            #pragma unroll
            for (int cf = 0; cf < 2; ++cf)
                #pragma unroll
                for (int ks = 0; ks < 2; ++ks) {
                    accE[rf][cf] = __builtin_amdgcn_mfma_f32_16x16x32_bf16(a[0][ks], Bf[0][cf][0][ks], accE[rf][cf], 0, 0, 0);
                    accE[rf][cf] = __builtin_amdgcn_mfma_f32_16x16x32_bf16(a[0][ks], Bf[1][cf][0][ks], accE[rf][cf], 0, 0, 0);
                    accE[rf][cf] = __builtin_amdgcn_mfma_f32_16x16x32_bf16(a[1][ks], Bf[0][cf][0][ks], accE[rf][cf], 0, 0, 0);
                    accO[rf][cf] = __builtin_amdgcn_mfma_f32_16x16x32_bf16(a[0][ks], Bf[0][cf][1][ks], accO[rf][cf], 0, 0, 0);
                    accO[rf][cf] = __builtin_amdgcn_mfma_f32_16x16x32_bf16(a[0][ks], Bf[1][cf][1][ks], accO[rf][cf], 0, 0, 0);
                    accO[rf][cf] = __builtin_amdgcn_mfma_f32_16x16x32_bf16(a[1][ks], Bf[0][cf][1][ks], accO[rf][cf], 0, 0, 0);
                }
        }
        __syncthreads();
    }
#undef STAGE

    // ---- epilogue: BN -> pool -> LIF, flag near-threshold pipelines ----
    #pragma unroll
    for (int rf = 0; rf < 4; ++rf) {
        const int site = rowblk * 32 + (wid >> 1) * 16 + rf * 4 + (lane >> 4);
        const int bI = site >> 10, nI = site & 1023;
        #pragma unroll
        for (int cf = 0; cf < 2; ++cf) {
            const int op = ((c0 + wc0 + cf * 32) >> 1) + (lane & 15);
            float v = 0.0f;
            bool flg = false;
            #pragma unroll
            for (int t = 0; t < 4; ++t) {
                float hE = accE[rf][cf][t] * invE[cf] + addE[cf];
                float hO = accO[rf][cf][t] * invO[cf] + addO[cf];
                float m = fmaxf(hE, hO);
                v = (v + m) * 0.5f;
                float dv = v - 1.0f;
                bool sp = dv >= 0.0f;
                out[(((size_t)t * 32 + bI) * 1024 + nI) * 256 + op] = sp ? 1.0f : 0.0f;
                flg |= (fabsf(dv) < 1e-3f);
                if (sp) v = 0.0f;
            }
            if (flg) {
                unsigned idx = atomicAdd(cnt, 1u);
                if (idx < CAP) list[idx] = ((unsigned)site << 8) | (unsigned)op;
            }
        }
    }
}

// ---------------- exact f64 repair of flagged pipelines ----------------
__global__ __launch_bounds__(256) void k_repair(
    const float* __restrict__ x, const float* __restrict__ W,
    const float* __restrict__ gamma, const float* __restrict__ beta,
    const float* __restrict__ rmean, const float* __restrict__ rvar,
    float* __restrict__ out, const unsigned* __restrict__ cnt,
    const unsigned* __restrict__ list)
{
    unsigned count = *cnt;
    if (count > CAP) count = CAP;
    for (unsigned j = blockIdx.x * 256 + threadIdx.x; j < count; j += 256u * 1024u) {
        const unsigned e = list[j];
        const int op = e & 255;
        const int site = e >> 8;
        const int bI = site >> 10, nI = site & 1023;

        double h[4][2];
        #pragma unroll
        for (int p = 0; p < 2; ++p) {
            const int c = 2 * op + p;
            const float* Wr = W + (size_t)c * D_;
            #pragma unroll
            for (int t = 0; t < 4; ++t) {
                const float* xr = x + (((size_t)t * 32 + bI) * 1024 + nI) * D_;
                double s0 = 0, s1 = 0, s2 = 0, s3 = 0;
                for (int d = 0; d < D_; d += 4) {
                    float4 xv = *(const float4*)(xr + d);
                    float4 wv = *(const float4*)(Wr + d);
                    s0 = fma((double)xv.x, (double)wv.x, s0);
                    s1 = fma((double)xv.y, (double)wv.y, s1);
                    s2 = fma((double)xv.z, (double)wv.z, s2);
                    s3 = fma((double)xv.w, (double)wv.w, s3);
                }
                h[t][p] = (s0 + s1) + (s2 + s3);
            }
        }
        double iv[2], ad[2];
        #pragma unroll
        for (int p = 0; p < 2; ++p) {
            const int c = 2 * op + p;
            iv[p] = (double)gamma[c] / sqrt((double)rvar[c] + 1e-5);
            ad[p] = (double)beta[c] - (double)rmean[c] * iv[p];
        }
        double v = 0.0;
        #pragma unroll
        for (int t = 0; t < 4; ++t) {
            double h0 = h[t][0] * iv[0] + ad[0];
            double h1 = h[t][1] * iv[1] + ad[1];
            double m = fmax(h0, h1);
            v = (v + m) * 0.5;
            const bool sp = (v >= 1.0);
            out[(((size_t)t * 32 + bI) * 1024 + nI) * 256 + op] = sp ? 1.0f : 0.0f;
            if (sp) v = 0.0;
        }
    }
}

// ---------------- fallback (round-1 exact f64 kernel) ----------------
constexpr int FB_SITES = 32, FB_ROWS = 128, FB_BN = 64, FB_BK = 16;

__global__ __launch_bounds__(256)
void snn_fused_f64(const float* __restrict__ x, const float* __restrict__ W,
                   const float* __restrict__ gamma, const float* __restrict__ beta,
                   const float* __restrict__ rmean, const float* __restrict__ rvar,
                   float* __restrict__ out)
{
    __shared__ float As[FB_BK][FB_ROWS];
    __shared__ float Bs[FB_BK][FB_BN];
    const int tid = threadIdx.x;
    const int tx = tid & 15, ty = tid >> 4;
    const int c0 = blockIdx.x * FB_BN;
    const int site_base = blockIdx.y * FB_SITES;
    const int b = site_base / N_, n0 = site_base % N_;
    const int lrow = tid >> 1, lk = (tid & 1) * 8;
    const int s_l = lrow >> 2, t_l = lrow & 3;
    const float* xrow = x + (size_t)((t_l * B_ + b) * N_ + (n0 + s_l)) * D_ + lk;
    const int wc = tid & 63, wk = (tid >> 6) * 4;
    const float* wrow = W + (size_t)(c0 + wc) * D_ + wk;
    double acc[8][4];
    #pragma unroll
    for (int i = 0; i < 8; ++i)
        #pragma unroll
        for (int j = 0; j < 4; ++j) acc[i][j] = 0.0;
    for (int k0 = 0; k0 < D_; k0 += FB_BK) {
        const float4 a0 = *(const float4*)(xrow + k0);
        const float4 a1 = *(const float4*)(xrow + k0 + 4);
        const float4 w4 = *(const float4*)(wrow + k0);
        As[lk + 0][lrow] = a0.x; As[lk + 1][lrow] = a0.y; As[lk + 2][lrow] = a0.z; As[lk + 3][lrow] = a0.w;
        As[lk + 4][lrow] = a1.x; As[lk + 5][lrow] = a1.y; As[lk + 6][lrow] = a1.z; As[lk + 7][lrow] = a1.w;
        Bs[wk + 0][wc] = w4.x; Bs[wk + 1][wc] = w4.y; Bs[wk + 2][wc] = w4.z; Bs[wk + 3][wc] = w4.w;
        __syncthreads();
        #pragma unroll
        for (int k = 0; k < FB_BK; ++k) {
            const float4 af0 = *(const float4*)&As[k][ty * 8];
            const float4 af1 = *(const float4*)&As[k][ty * 8 + 4];
            const float4 bf = *(const float4*)&Bs[k][tx * 4];
            const double ad[8] = {(double)af0.x, (double)af0.y, (double)af0.z, (double)af0.w,
                                  (double)af1.x, (double)af1.y, (double)af1.z, (double)af1.w};
            const double bd[4] = {(double)bf.x, (double)bf.y, (double)bf.z, (double)bf.w};
            #pragma unroll
            for (int i = 0; i < 8; ++i)
                #pragma unroll
                for (int j = 0; j < 4; ++j) acc[i][j] = fma(ad[i], bd[j], acc[i][j]);
        }
        __syncthreads();
    }
    double invd[4], addd[4];
    #pragma unroll
    for (int j = 0; j < 4; ++j) {
        const int c = c0 + tx * 4 + j;
        const double ivv = (double)gamma[c] / sqrt((double)rvar[c] + 1e-5);
        invd[j] = ivv; addd[j] = (double)beta[c] - (double)rmean[c] * ivv;
    }
    #pragma unroll
    for (int si = 0; si < 2; ++si) {
        const int n = n0 + ty * 2 + si;
        #pragma unroll
        for (int p = 0; p < 2; ++p) {
            const int op = (c0 >> 1) + tx * 2 + p;
            double v = 0.0;
            #pragma unroll
            for (int t = 0; t < 4; ++t) {
                const int i = si * 4 + t;
                const double h0 = acc[i][2 * p] * invd[2 * p] + addd[2 * p];
                const double h1 = acc[i][2 * p + 1] * invd[2 * p + 1] + addd[2 * p + 1];
                const double m = fmax(h0, h1);
                v = v + (m - v) * 0.5;
                const bool sp = (v >= 1.0);
                out[((size_t)(t * B_ + b) * N_ + n) * OP_ + op] = sp ? 1.0f : 0.0f;
                if (sp) v = 0.0;
            }
        }
    }
}

extern "C" void kernel_launch(void* const* d_in, const int* in_sizes, int n_in,
                              void* d_out, int out_size, void* d_ws, size_t ws_size,
                              hipStream_t stream)
{
    const float* x     = (const float*)d_in[0];
    const float* W     = (const float*)d_in[1];
    const float* gamma = (const float*)d_in[2];
    const float* beta  = (const float*)d_in[3];
    const float* rmean = (const float*)d_in[4];
    const float* rvar  = (const float*)d_in[5];
    float* out = (float*)d_out;

    if (ws_size < WS_NEED) {
        dim3 grid(O_ / FB_BN, (B_ * N_) / FB_SITES);
        snn_fused_f64<<<grid, dim3(256), 0, stream>>>(x, W, gamma, beta, rmean, rvar, out);
        return;
    }

    char* ws = (char*)d_ws;
    unsigned* cnt = (unsigned*)(ws + WS_CNT);
    unsigned short* wh = (unsigned short*)(ws + WS_WH);
    unsigned short* wm = (unsigned short*)(ws + WS_WM);
    unsigned short* xh = (unsigned short*)(ws + WS_XH);
    unsigned short* xm = (unsigned short*)(ws + WS_XM);
    unsigned* list = (unsigned*)(ws + WS_LIST);

    k_init<<<1, 64, 0, stream>>>(cnt);
    k_split_w<<<512, 256, 0, stream>>>(W, wh, wm);
    k_split_x<<<M_, 128, 0, stream>>>(x, xh, xm);
    k_gemm<<<4096, 256, 65536, stream>>>(xh, xm, wh, wm, gamma, beta, rmean, rvar, out, cnt, list);
    k_repair<<<1024, 256, 0, stream>>>(x, W, gamma, beta, rmean, rvar, out, cnt, list);
}

// Round 3
// 522.289 us; speedup vs baseline: 2.8077x; 1.3258x over previous
//
#include <hip/hip_runtime.h>

constexpr int T_ = 4, B_ = 32, N_ = 1024, D_ = 512, O_ = 512, OP_ = 256;
constexpr int M_ = T_ * B_ * N_;               // 131072 GEMM rows (ordered site*4 + t)
constexpr unsigned CAP = 1u * 1024 * 1024;     // repair-list capacity

// ---- ws layout (bytes) ----
constexpr size_t WS_CNT  = 0;
constexpr size_t WS_WH   = 1u << 20;
constexpr size_t WS_WM   = WS_WH + (size_t)O_ * D_ * 2;
constexpr size_t WS_XH   = 2u << 20;
constexpr size_t WS_XM   = WS_XH + (size_t)M_ * D_ * 2;
constexpr size_t WS_LIST = WS_XM + (size_t)M_ * D_ * 2;
constexpr size_t WS_NEED = WS_LIST + (size_t)CAP * 4;

typedef __attribute__((ext_vector_type(8))) short bf8;
typedef __attribute__((ext_vector_type(4))) float f4;

__device__ __forceinline__ unsigned short f2bf(float f) {
    unsigned u = __float_as_uint(f);
    unsigned r = (u + 0x7FFFu + ((u >> 16) & 1u)) >> 16;   // RNE
    return (unsigned short)r;
}
__device__ __forceinline__ float bf2f(unsigned short h) {
    return __uint_as_float(((unsigned)h) << 16);
}

// ---------------- prep: split x (with t-minor reorder), split W, reset cnt ----------------
__global__ __launch_bounds__(256) void k_prep(
    const float* __restrict__ x, const float* __restrict__ W,
    unsigned short* __restrict__ xh, unsigned short* __restrict__ xm,
    unsigned short* __restrict__ wh, unsigned short* __restrict__ wm,
    unsigned* __restrict__ cnt)
{
    if (blockIdx.x == 0 && threadIdx.x == 0) *cnt = 0u;
    const unsigned stride = gridDim.x * 256u;
    const unsigned t0 = blockIdx.x * 256u + threadIdx.x;

    // x: 16,777,216 float4 chunks; row = i>>7 (512 f32 per row), d4 = i&127
    for (unsigned i = t0; i < (unsigned)(M_ * 128); i += stride) {
        const unsigned row = i >> 7;
        const unsigned d4 = i & 127u;
        const unsigned t = row >> 15, b = (row >> 10) & 31u, n = row & 1023u;
        const unsigned rout = (((b << 10) | n) << 2) | t;
        const float4 v = *(const float4*)(x + ((size_t)row << 9) + (d4 << 2));
        const unsigned short h0 = f2bf(v.x), h1 = f2bf(v.y), h2 = f2bf(v.z), h3 = f2bf(v.w);
        const unsigned short m0 = f2bf(v.x - bf2f(h0)), m1 = f2bf(v.y - bf2f(h1));
        const unsigned short m2 = f2bf(v.z - bf2f(h2)), m3 = f2bf(v.w - bf2f(h3));
        *(ushort4*)(xh + ((size_t)rout << 9) + (d4 << 2)) = make_ushort4(h0, h1, h2, h3);
        *(ushort4*)(xm + ((size_t)rout << 9) + (d4 << 2)) = make_ushort4(m0, m1, m2, m3);
    }
    // W: 65536 float4 chunks
    for (unsigned i = t0; i < (unsigned)(O_ * D_ / 4); i += stride) {
        const float4 v = *(const float4*)(W + ((size_t)i << 2));
        const unsigned short h0 = f2bf(v.x), h1 = f2bf(v.y), h2 = f2bf(v.z), h3 = f2bf(v.w);
        const unsigned short m0 = f2bf(v.x - bf2f(h0)), m1 = f2bf(v.y - bf2f(h1));
        const unsigned short m2 = f2bf(v.z - bf2f(h2)), m3 = f2bf(v.w - bf2f(h3));
        *(ushort4*)(wh + ((size_t)i << 2)) = make_ushort4(h0, h1, h2, h3);
        *(ushort4*)(wm + ((size_t)i << 2)) = make_ushort4(m0, m1, m2, m3);
    }
}

// ---------------- fast fused pass: MFMA GEMM + BN/pool/LIF + flagging ----------------
__global__ __launch_bounds__(256) void k_gemm(
    const unsigned short* __restrict__ xh, const unsigned short* __restrict__ xm,
    const unsigned short* __restrict__ wh, const unsigned short* __restrict__ wm,
    const float* __restrict__ gamma, const float* __restrict__ beta,
    const float* __restrict__ rmean, const float* __restrict__ rvar,
    float* __restrict__ out, unsigned* __restrict__ cnt, unsigned* __restrict__ list)
{
    extern __shared__ char lds[];   // [dbuf:2][term:2][row:128][128B], 64 KiB
    const int tid  = threadIdx.x;
    const int lane = tid & 63;
    const int wid  = tid >> 6;

    // XCD-aware swizzle: each XCD gets a contiguous range of work ids
    const int dd = blockIdx.x;                  // 0..4095
    const int w  = (dd & 7) * 512 + (dd >> 3);
    const int colblk = w & 3, rowblk = w >> 2;
    const int c0  = colblk * 128;
    const int wr0 = (wid >> 1) * 64, wc0 = (wid & 1) * 64;

    // ---- staging source (pre-swizzled so linear LDS dest = swizzled layout) ----
    const int srow = tid >> 3;                              // 0..31
    const int skb  = ((tid & 7) << 4) ^ ((srow & 7) << 4);  // byte within 128B row
    const char* gA0 = (const char*)xh + ((size_t)(rowblk * 128 + srow)) * 1024 + skb;
    const char* gA1 = (const char*)xm + ((size_t)(rowblk * 128 + srow)) * 1024 + skb;

    // ---- B per-lane byte offsets: even/odd column split ----
    size_t bOff[2][2];  // [cf][eo]
    #pragma unroll
    for (int cf = 0; cf < 2; ++cf)
        #pragma unroll
        for (int eo = 0; eo < 2; ++eo) {
            int c = c0 + wc0 + cf * 32 + 2 * (lane & 15) + eo;
            bOff[cf][eo] = (size_t)c * 1024 + ((size_t)(lane >> 4) << 4);
        }

    // ---- BN constants (f32; any deviation covered by flag+repair) ----
    float invE[2], addE[2], invO[2], addO[2];
    #pragma unroll
    for (int cf = 0; cf < 2; ++cf) {
        int cE = c0 + wc0 + cf * 32 + 2 * (lane & 15);
        int cO = cE + 1;
        float ivE = gamma[cE] / sqrtf(rvar[cE] + 1e-5f);
        float ivO = gamma[cO] / sqrtf(rvar[cO] + 1e-5f);
        invE[cf] = ivE; addE[cf] = beta[cE] - rmean[cE] * ivE;
        invO[cf] = ivO; addO[cf] = beta[cO] - rmean[cO] * ivO;
    }

    f4 accE[4][2], accO[4][2];
    #pragma unroll
    for (int i = 0; i < 4; ++i)
        #pragma unroll
        for (int j = 0; j < 2; ++j) { accE[i][j] = (f4)0.0f; accO[i][j] = (f4)0.0f; }

#define STAGE(buf, step)                                                                   \
    {                                                                                      \
        _Pragma("unroll")                                                                  \
        for (int i = 0; i < 4; ++i) {                                                      \
            __builtin_amdgcn_global_load_lds(                                              \
                (const __attribute__((address_space(1))) void*)(gA0 + (size_t)i * 32768 +  \
                                                                (step) * 128),             \
                (__attribute__((address_space(3))) void*)(lds + (buf) * 32768 + 0 +        \
                                                          i * 4096 + wid * 1024),          \
                16, 0, 0);                                                                 \
            __builtin_amdgcn_global_load_lds(                                              \
                (const __attribute__((address_space(1))) void*)(gA1 + (size_t)i * 32768 +  \
                                                                (step) * 128),             \
                (__attribute__((address_space(3))) void*)(lds + (buf) * 32768 + 16384 +    \
                                                          i * 4096 + wid * 1024),          \
                16, 0, 0);                                                                 \
        }                                                                                  \
    }

    const char* whB = (const char*)wh;
    const char* wmB = (const char*)wm;

    // B-fragment register double-buffer: [parity][term][cf][eo][ks]
    bf8 Bbuf[2][2][2][2][2];
#define LOADB(P, STEP)                                                                     \
    {                                                                                      \
        _Pragma("unroll")                                                                  \
        for (int cf = 0; cf < 2; ++cf)                                                     \
            _Pragma("unroll")                                                              \
            for (int eo = 0; eo < 2; ++eo)                                                 \
                _Pragma("unroll")                                                          \
                for (int ks = 0; ks < 2; ++ks) {                                           \
                    Bbuf[P][0][cf][eo][ks] =                                               \
                        *(const bf8*)(whB + bOff[cf][eo] + (STEP)*128 + ks * 64);          \
                    Bbuf[P][1][cf][eo][ks] =                                               \
                        *(const bf8*)(wmB + bOff[cf][eo] + (STEP)*128 + ks * 64);          \
                }                                                                          \
    }

    STAGE(0, 0);
    LOADB(0, 0);
    __syncthreads();

    #pragma unroll
    for (int step = 0; step < 8; ++step) {
        const int dbuf = step & 1;
        if (step < 7) {
            STAGE(dbuf ^ 1, step + 1);
            LOADB(dbuf ^ 1, step + 1);   // prefetch next B during this step's MFMA
        }

        #pragma unroll
        for (int rf = 0; rf < 4; ++rf) {
            const int row = wr0 + rf * 16 + (lane & 15);
            const int X = (row & 7) << 4;
            const char* ab = lds + dbuf * 32768 + row * 128;
            bf8 a[2][2];  // [term][ksub]
            #pragma unroll
            for (int ks = 0; ks < 2; ++ks) {
                const int cb = ks * 64 + ((lane >> 4) << 4);
                a[0][ks] = *(const bf8*)(ab + 0     + (cb ^ X));
                a[1][ks] = *(const bf8*)(ab + 16384 + (cb ^ X));
            }
            #pragma unroll
            for (int cf = 0; cf < 2; ++cf)
                #pragma unroll
                for (int ks = 0; ks < 2; ++ks) {
                    accE[rf][cf] = __builtin_amdgcn_mfma_f32_16x16x32_bf16(a[0][ks], Bbuf[dbuf][0][cf][0][ks], accE[rf][cf], 0, 0, 0);
                    accE[rf][cf] = __builtin_amdgcn_mfma_f32_16x16x32_bf16(a[0][ks], Bbuf[dbuf][1][cf][0][ks], accE[rf][cf], 0, 0, 0);
                    accE[rf][cf] = __builtin_amdgcn_mfma_f32_16x16x32_bf16(a[1][ks], Bbuf[dbuf][0][cf][0][ks], accE[rf][cf], 0, 0, 0);
                    accO[rf][cf] = __builtin_amdgcn_mfma_f32_16x16x32_bf16(a[0][ks], Bbuf[dbuf][0][cf][1][ks], accO[rf][cf], 0, 0, 0);
                    accO[rf][cf] = __builtin_amdgcn_mfma_f32_16x16x32_bf16(a[0][ks], Bbuf[dbuf][1][cf][1][ks], accO[rf][cf], 0, 0, 0);
                    accO[rf][cf] = __builtin_amdgcn_mfma_f32_16x16x32_bf16(a[1][ks], Bbuf[dbuf][0][cf][1][ks], accO[rf][cf], 0, 0, 0);
                }
        }
        __syncthreads();
    }
#undef STAGE
#undef LOADB

    // ---- epilogue: BN -> pool -> LIF, flag near-threshold pipelines ----
    #pragma unroll
    for (int rf = 0; rf < 4; ++rf) {
        const int site = rowblk * 32 + (wid >> 1) * 16 + rf * 4 + (lane >> 4);
        const int bI = site >> 10, nI = site & 1023;
        #pragma unroll
        for (int cf = 0; cf < 2; ++cf) {
            const int op = ((c0 + wc0 + cf * 32) >> 1) + (lane & 15);
            float v = 0.0f;
            bool flg = false;
            #pragma unroll
            for (int t = 0; t < 4; ++t) {
                float hE = accE[rf][cf][t] * invE[cf] + addE[cf];
                float hO = accO[rf][cf][t] * invO[cf] + addO[cf];
                float m = fmaxf(hE, hO);
                v = (v + m) * 0.5f;
                float dv = v - 1.0f;
                bool sp = dv >= 0.0f;
                out[(((size_t)t * 32 + bI) * 1024 + nI) * 256 + op] = sp ? 1.0f : 0.0f;
                flg |= (fabsf(dv) < 2e-4f);
                if (sp) v = 0.0f;
            }
            if (flg) {
                unsigned idx = atomicAdd(cnt, 1u);
                if (idx < CAP) list[idx] = ((unsigned)site << 8) | (unsigned)op;
            }
        }
    }
}

// ---------------- exact f64 repair of flagged pipelines ----------------
__global__ __launch_bounds__(256) void k_repair(
    const float* __restrict__ x, const float* __restrict__ W,
    const float* __restrict__ gamma, const float* __restrict__ beta,
    const float* __restrict__ rmean, const float* __restrict__ rvar,
    float* __restrict__ out, const unsigned* __restrict__ cnt,
    const unsigned* __restrict__ list)
{
    unsigned count = *cnt;
    if (count > CAP) count = CAP;
    for (unsigned j = blockIdx.x * 256 + threadIdx.x; j < count; j += 256u * 256u) {
        const unsigned e = list[j];
        const int op = e & 255;
        const int site = e >> 8;
        const int bI = site >> 10, nI = site & 1023;

        double h[4][2];
        #pragma unroll
        for (int p = 0; p < 2; ++p) {
            const int c = 2 * op + p;
            const float* Wr = W + (size_t)c * D_;
            #pragma unroll
            for (int t = 0; t < 4; ++t) {
                const float* xr = x + (((size_t)t * 32 + bI) * 1024 + nI) * D_;
                double s0 = 0, s1 = 0, s2 = 0, s3 = 0;
                for (int d = 0; d < D_; d += 4) {
                    float4 xv = *(const float4*)(xr + d);
                    float4 wv = *(const float4*)(Wr + d);
                    s0 = fma((double)xv.x, (double)wv.x, s0);
                    s1 = fma((double)xv.y, (double)wv.y, s1);
                    s2 = fma((double)xv.z, (double)wv.z, s2);
                    s3 = fma((double)xv.w, (double)wv.w, s3);
                }
                h[t][p] = (s0 + s1) + (s2 + s3);
            }
        }
        double iv[2], ad[2];
        #pragma unroll
        for (int p = 0; p < 2; ++p) {
            const int c = 2 * op + p;
            iv[p] = (double)gamma[c] / sqrt((double)rvar[c] + 1e-5);
            ad[p] = (double)beta[c] - (double)rmean[c] * iv[p];
        }
        double v = 0.0;
        #pragma unroll
        for (int t = 0; t < 4; ++t) {
            double h0 = h[t][0] * iv[0] + ad[0];
            double h1 = h[t][1] * iv[1] + ad[1];
            double m = fmax(h0, h1);
            v = (v + m) * 0.5;
            const bool sp = (v >= 1.0);
            out[(((size_t)t * 32 + bI) * 1024 + nI) * 256 + op] = sp ? 1.0f : 0.0f;
            if (sp) v = 0.0;
        }
    }
}

// ---------------- fallback (round-1 exact f64 kernel) ----------------
constexpr int FB_SITES = 32, FB_ROWS = 128, FB_BN = 64, FB_BK = 16;

__global__ __launch_bounds__(256)
void snn_fused_f64(const float* __restrict__ x, const float* __restrict__ W,
                   const float* __restrict__ gamma, const float* __restrict__ beta,
                   const float* __restrict__ rmean, const float* __restrict__ rvar,
                   float* __restrict__ out)
{
    __shared__ float As[FB_BK][FB_ROWS];
    __shared__ float Bs[FB_BK][FB_BN];
    const int tid = threadIdx.x;
    const int tx = tid & 15, ty = tid >> 4;
    const int c0 = blockIdx.x * FB_BN;
    const int site_base = blockIdx.y * FB_SITES;
    const int b = site_base / N_, n0 = site_base % N_;
    const int lrow = tid >> 1, lk = (tid & 1) * 8;
    const int s_l = lrow >> 2, t_l = lrow & 3;
    const float* xrow = x + (size_t)((t_l * B_ + b) * N_ + (n0 + s_l)) * D_ + lk;
    const int wc = tid & 63, wk = (tid >> 6) * 4;
    const float* wrow = W + (size_t)(c0 + wc) * D_ + wk;
    double acc[8][4];
    #pragma unroll
    for (int i = 0; i < 8; ++i)
        #pragma unroll
        for (int j = 0; j < 4; ++j) acc[i][j] = 0.0;
    for (int k0 = 0; k0 < D_; k0 += FB_BK) {
        const float4 a0 = *(const float4*)(xrow + k0);
        const float4 a1 = *(const float4*)(xrow + k0 + 4);
        const float4 w4 = *(const float4*)(wrow + k0);
        As[lk + 0][lrow] = a0.x; As[lk + 1][lrow] = a0.y; As[lk + 2][lrow] = a0.z; As[lk + 3][lrow] = a0.w;
        As[lk + 4][lrow] = a1.x; As[lk + 5][lrow] = a1.y; As[lk + 6][lrow] = a1.z; As[lk + 7][lrow] = a1.w;
        Bs[wk + 0][wc] = w4.x; Bs[wk + 1][wc] = w4.y; Bs[wk + 2][wc] = w4.z; Bs[wk + 3][wc] = w4.w;
        __syncthreads();
        #pragma unroll
        for (int k = 0; k < FB_BK; ++k) {
            const float4 af0 = *(const float4*)&As[k][ty * 8];
            const float4 af1 = *(const float4*)&As[k][ty * 8 + 4];
            const float4 bf = *(const float4*)&Bs[k][tx * 4];
            const double ad[8] = {(double)af0.x, (double)af0.y, (double)af0.z, (double)af0.w,
                                  (double)af1.x, (double)af1.y, (double)af1.z, (double)af1.w};
            const double bd[4] = {(double)bf.x, (double)bf.y, (double)bf.z, (double)bf.w};
            #pragma unroll
            for (int i = 0; i < 8; ++i)
                #pragma unroll
                for (int j = 0; j < 4; ++j) acc[i][j] = fma(ad[i], bd[j], acc[i][j]);
        }
        __syncthreads();
    }
    double invd[4], addd[4];
    #pragma unroll
    for (int j = 0; j < 4; ++j) {
        const int c = c0 + tx * 4 + j;
        const double ivv = (double)gamma[c] / sqrt((double)rvar[c] + 1e-5);
        invd[j] = ivv; addd[j] = (double)beta[c] - (double)rmean[c] * ivv;
    }
    #pragma unroll
    for (int si = 0; si < 2; ++si) {
        const int n = n0 + ty * 2 + si;
        #pragma unroll
        for (int p = 0; p < 2; ++p) {
            const int op = (c0 >> 1) + tx * 2 + p;
            double v = 0.0;
            #pragma unroll
            for (int t = 0; t < 4; ++t) {
                const int i = si * 4 + t;
                const double h0 = acc[i][2 * p] * invd[2 * p] + addd[2 * p];
                const double h1 = acc[i][2 * p + 1] * invd[2 * p + 1] + addd[2 * p + 1];
                const double m = fmax(h0, h1);
                v = v + (m - v) * 0.5;
                const bool sp = (v >= 1.0);
                out[((size_t)(t * B_ + b) * N_ + n) * OP_ + op] = sp ? 1.0f : 0.0f;
                if (sp) v = 0.0;
            }
        }
    }
}

extern "C" void kernel_launch(void* const* d_in, const int* in_sizes, int n_in,
                              void* d_out, int out_size, void* d_ws, size_t ws_size,
                              hipStream_t stream)
{
    const float* x     = (const float*)d_in[0];
    const float* W     = (const float*)d_in[1];
    const float* gamma = (const float*)d_in[2];
    const float* beta  = (const float*)d_in[3];
    const float* rmean = (const float*)d_in[4];
    const float* rvar  = (const float*)d_in[5];
    float* out = (float*)d_out;

    if (ws_size < WS_NEED) {
        dim3 grid(O_ / FB_BN, (B_ * N_) / FB_SITES);
        snn_fused_f64<<<grid, dim3(256), 0, stream>>>(x, W, gamma, beta, rmean, rvar, out);
        return;
    }

    char* ws = (char*)d_ws;
    unsigned* cnt = (unsigned*)(ws + WS_CNT);
    unsigned short* wh = (unsigned short*)(ws + WS_WH);
    unsigned short* wm = (unsigned short*)(ws + WS_WM);
    unsigned short* xh = (unsigned short*)(ws + WS_XH);
    unsigned short* xm = (unsigned short*)(ws + WS_XM);
    unsigned* list = (unsigned*)(ws + WS_LIST);

    k_prep<<<4096, 256, 0, stream>>>(x, W, xh, xm, wh, wm, cnt);
    k_gemm<<<4096, 256, 65536, stream>>>(xh, xm, wh, wm, gamma, beta, rmean, rvar, out, cnt, list);
    k_repair<<<256, 256, 0, stream>>>(x, W, gamma, beta, rmean, rvar, out, cnt, list);
}